// Round 3
// baseline (4065.313 us; speedup 1.0000x reference)
//
#include <hip/hip_runtime.h>

// Model dims
#define T_ 64
#define B_ 1024
#define V_ 128
#define H_ 512

__device__ __forceinline__ unsigned short f2bf(float f) {
    union { float f; unsigned int i; } v; v.f = f;
    unsigned int x = v.i;
    return (unsigned short)((x + 0x7FFFu + ((x >> 16) & 1u)) >> 16);
}
__device__ __forceinline__ float bf2f(unsigned short u) {
    union { unsigned int i; float f; } v; v.i = ((unsigned int)u) << 16; return v.f;
}

// ---------------- init: h=c=0, cbias = xh_b + hh_b ----------------
__global__ __launch_bounds__(256) void init_k(const float* __restrict__ xh_b,
                                              const float* __restrict__ hh_b,
                                              float* __restrict__ h, float* __restrict__ c,
                                              float* __restrict__ cbias) {
    int i = blockIdx.x * 256 + threadIdx.x;          // grid covers B_*H_ exactly
    h[i] = 0.f; c[i] = 0.f;
    if (i < 4 * H_) cbias[i] = xh_b[i] + hh_b[i];
}

// ---------------- conv1 3x3 pad1 + relu + 2x2 maxpool ----------------
// out: [B,8,32,32] fp32, one thread per pooled output
__global__ __launch_bounds__(256) void conv1_k(const float* __restrict__ img,
                                               const float* __restrict__ w,
                                               const float* __restrict__ bias,
                                               float* __restrict__ out) {
    int id = blockIdx.x * 256 + threadIdx.x;         // B*8*32*32 = 8388608
    int px = id & 31, py = (id >> 5) & 31, oc = (id >> 10) & 7, b = id >> 13;
    const float* ip = img + b * 4096;
    float wv[9];
#pragma unroll
    for (int t = 0; t < 9; ++t) wv[t] = w[oc * 9 + t];
    float bs = bias[oc];
    float m = -3.4e38f;
#pragma unroll
    for (int sy = 0; sy < 2; ++sy)
#pragma unroll
    for (int sx = 0; sx < 2; ++sx) {
        int oy = 2 * py + sy, ox = 2 * px + sx;
        float acc = bs;
#pragma unroll
        for (int ky = 0; ky < 3; ++ky) {
            int iy = oy + ky - 1;
            if (iy < 0 || iy > 63) continue;
#pragma unroll
            for (int kx = 0; kx < 3; ++kx) {
                int ix = ox + kx - 1;
                if (ix < 0 || ix > 63) continue;
                acc += ip[iy * 64 + ix] * wv[ky * 3 + kx];
            }
        }
        m = fmaxf(m, acc);
    }
    out[id] = fmaxf(m, 0.f);
}

// ---------------- conv2 5x5 pad1 + relu + 2x2 maxpool ----------------
// one image per block; zero-padded input (8x34x34) + weights staged in LDS
__global__ __launch_bounds__(256) void conv2_k(const float* __restrict__ in,
                                               const float* __restrict__ w,
                                               const float* __restrict__ bias,
                                               float* __restrict__ feat) {
    __shared__ float in_s[8 * 34 * 34];
    __shared__ float w_s[3200];
    __shared__ float b_s[16];
    int tid = threadIdx.x, b = blockIdx.x;
    for (int e = tid; e < 8 * 34 * 34; e += 256) {
        int ic = e / 1156, r = e - ic * 1156;
        int y = r / 34, xx = r - y * 34;
        float v = 0.f;
        if (y >= 1 && y <= 32 && xx >= 1 && xx <= 32)
            v = in[b * 8192 + ic * 1024 + (y - 1) * 32 + (xx - 1)];
        in_s[e] = v;
    }
    for (int e = tid; e < 3200; e += 256) w_s[e] = w[e];
    if (tid < 16) b_s[tid] = bias[tid];
    __syncthreads();
    for (int o = tid; o < 3600; o += 256) {
        int oc = o / 225, p = o - oc * 225;
        int py = p / 15, px = p - py * 15;
        float a00, a01, a10, a11;
        a00 = a01 = a10 = a11 = b_s[oc];
        for (int ic = 0; ic < 8; ++ic) {
            const float* ip = in_s + ic * 1156 + 2 * py * 34 + 2 * px;
            const float* wp = w_s + (oc * 8 + ic) * 25;
#pragma unroll
            for (int ky = 0; ky < 5; ++ky)
#pragma unroll
            for (int kx = 0; kx < 5; ++kx) {
                float wv = wp[ky * 5 + kx];
                a00 += ip[(ky    ) * 34 + kx    ] * wv;
                a01 += ip[(ky    ) * 34 + kx + 1] * wv;
                a10 += ip[(ky + 1) * 34 + kx    ] * wv;
                a11 += ip[(ky + 1) * 34 + kx + 1] * wv;
            }
        }
        float mx = fmaxf(fmaxf(a00, a01), fmaxf(a10, a11));
        feat[b * 3600 + o] = fmaxf(mx, 0.f);
    }
}

// ---------------- imgfc: e = relu(feat @ W + b), M=1024 N=512 K=3600 ----------------
__global__ __launch_bounds__(256) void imgfc_gemm(const float* __restrict__ A,
                                                  const float* __restrict__ W,
                                                  const float* __restrict__ bias,
                                                  float* __restrict__ E) {
    __shared__ __align__(16) float As[16][68];
    __shared__ __align__(16) float Bs[16][68];
    const int tid = threadIdx.x;
    const int tx = tid & 15, ty = tid >> 4;
    const int row0 = blockIdx.y * 64, col0 = blockIdx.x * 64;
    const int am = tid >> 2, ak = (tid & 3) * 4;
    const int bk = tid >> 4, bn = (tid & 15) * 4;
    float acc[4][4] = {};
    for (int k0 = 0; k0 < 3600; k0 += 16) {
        float4 fa = *(const float4*)(A + (row0 + am) * 3600 + k0 + ak);
        float4 fb = *(const float4*)(W + (k0 + bk) * 512 + col0 + bn);
        __syncthreads();
        As[ak + 0][am] = fa.x; As[ak + 1][am] = fa.y; As[ak + 2][am] = fa.z; As[ak + 3][am] = fa.w;
        Bs[bk][bn + 0] = fb.x; Bs[bk][bn + 1] = fb.y; Bs[bk][bn + 2] = fb.z; Bs[bk][bn + 3] = fb.w;
        __syncthreads();
#pragma unroll
        for (int kk = 0; kk < 16; ++kk) {
            float4 av = *(const float4*)(&As[kk][ty * 4]);
            float4 bv = *(const float4*)(&Bs[kk][tx * 4]);
            float a[4] = {av.x, av.y, av.z, av.w};
            float bb[4] = {bv.x, bv.y, bv.z, bv.w};
#pragma unroll
            for (int i = 0; i < 4; ++i)
#pragma unroll
            for (int j = 0; j < 4; ++j) acc[i][j] += a[i] * bb[j];
        }
    }
#pragma unroll
    for (int i = 0; i < 4; ++i) {
        int r = row0 + ty * 4 + i;
#pragma unroll
        for (int j = 0; j < 4; ++j) {
            int cI = col0 + tx * 4 + j;
            E[r * 512 + cI] = fmaxf(acc[i][j] + bias[cI], 0.f);
        }
    }
}

// ---------------- gates = [x_t | h] @ [[xh_w],[hh_w]] + cbias (+ img4 at t0) ----------------
// M=1024, N=2048, K=640 (128 x-part + 512 h-part), all fp32
__global__ __launch_bounds__(256) void gates_gemm(const float* __restrict__ x,
                                                  const float* __restrict__ h,
                                                  const float* __restrict__ xw,
                                                  const float* __restrict__ hw,
                                                  const float* __restrict__ cbias,
                                                  const float* __restrict__ eimg,
                                                  float* __restrict__ gates, int addImg) {
    __shared__ __align__(16) float As[16][68];
    __shared__ __align__(16) float Bs[16][68];
    const int tid = threadIdx.x;
    const int tx = tid & 15, ty = tid >> 4;
    const int row0 = blockIdx.y * 64, col0 = blockIdx.x * 64;
    const int am = tid >> 2, ak = (tid & 3) * 4;
    const int bk = tid >> 4, bn = (tid & 15) * 4;
    float acc[4][4] = {};
    for (int k0 = 0; k0 < 640; k0 += 16) {
        float4 fa, fb;
        if (k0 < 128) {
            fa = *(const float4*)(x + (row0 + am) * 128 + k0 + ak);
            fb = *(const float4*)(xw + (k0 + bk) * 2048 + col0 + bn);
        } else {
            fa = *(const float4*)(h + (row0 + am) * 512 + (k0 - 128) + ak);
            fb = *(const float4*)(hw + (k0 - 128 + bk) * 2048 + col0 + bn);
        }
        __syncthreads();
        As[ak + 0][am] = fa.x; As[ak + 1][am] = fa.y; As[ak + 2][am] = fa.z; As[ak + 3][am] = fa.w;
        Bs[bk][bn + 0] = fb.x; Bs[bk][bn + 1] = fb.y; Bs[bk][bn + 2] = fb.z; Bs[bk][bn + 3] = fb.w;
        __syncthreads();
#pragma unroll
        for (int kk = 0; kk < 16; ++kk) {
            float4 av = *(const float4*)(&As[kk][ty * 4]);
            float4 bv = *(const float4*)(&Bs[kk][tx * 4]);
            float a[4] = {av.x, av.y, av.z, av.w};
            float bb[4] = {bv.x, bv.y, bv.z, bv.w};
#pragma unroll
            for (int i = 0; i < 4; ++i)
#pragma unroll
            for (int j = 0; j < 4; ++j) acc[i][j] += a[i] * bb[j];
        }
    }
#pragma unroll
    for (int i = 0; i < 4; ++i) {
        int r = row0 + ty * 4 + i;
#pragma unroll
        for (int j = 0; j < 4; ++j) {
            int cI = col0 + tx * 4 + j;
            float v = acc[i][j] + cbias[cI];
            if (addImg) v += eimg[r * 512 + (cI & 511)];
            gates[r * 2048 + cI] = v;
        }
    }
}

// ---------------- LSTM cell elementwise ----------------
__global__ __launch_bounds__(256) void cell_k(const float* __restrict__ gates,
                                              float* __restrict__ h, float* __restrict__ c,
                                              unsigned short* __restrict__ hs_t) {
    int i = blockIdx.x * 256 + threadIdx.x;          // B_*H_ exactly
    int b = i >> 9, j = i & 511;
    const float* g = gates + b * 2048;
    float iv = g[j], fv = g[j + 512], gv = g[j + 1024], ov = g[j + 1536];
    iv = 1.f / (1.f + expf(-iv));
    fv = 1.f / (1.f + expf(-fv));
    gv = tanhf(gv);
    ov = 1.f / (1.f + expf(-ov));
    float cn = fv * c[i] + iv * gv;
    float hn = ov * tanhf(cn);
    c[i] = cn; h[i] = hn;
    hs_t[i] = f2bf(hn);
}

// ---------------- logits + log_softmax, 4 rows per block, fp32 out ----------------
__global__ __launch_bounds__(128) void logits_k(const unsigned short* __restrict__ hs,
                                                const float* __restrict__ ow,
                                                const float* __restrict__ ob,
                                                float* __restrict__ out) {
    __shared__ float hrow[4][512];
    __shared__ float ls[4][128];
    __shared__ float lz[4];
    int tid = threadIdx.x;
    int row0 = blockIdx.x * 4;
    for (int e = tid; e < 2048; e += 128) {
        int r = e >> 9, cc = e & 511;
        hrow[r][cc] = bf2f(hs[(row0 + r) * 512 + cc]);
    }
    __syncthreads();
    float bb = ob[tid];
    float acc0 = bb, acc1 = bb, acc2 = bb, acc3 = bb;
#pragma unroll 4
    for (int k = 0; k < 512; ++k) {
        float w = ow[k * 128 + tid];
        acc0 += hrow[0][k] * w;
        acc1 += hrow[1][k] * w;
        acc2 += hrow[2][k] * w;
        acc3 += hrow[3][k] * w;
    }
    ls[0][tid] = acc0; ls[1][tid] = acc1; ls[2][tid] = acc2; ls[3][tid] = acc3;
    __syncthreads();
    int g = tid >> 5, lane = tid & 31;
    float v0 = ls[g][lane], v1 = ls[g][lane + 32], v2 = ls[g][lane + 64], v3 = ls[g][lane + 96];
    float m = fmaxf(fmaxf(v0, v1), fmaxf(v2, v3));
#pragma unroll
    for (int off = 16; off > 0; off >>= 1) m = fmaxf(m, __shfl_xor(m, off, 32));
    float s = expf(v0 - m) + expf(v1 - m) + expf(v2 - m) + expf(v3 - m);
#pragma unroll
    for (int off = 16; off > 0; off >>= 1) s += __shfl_xor(s, off, 32);
    if (lane == 0) lz[g] = m + logf(s);
    __syncthreads();
    float z0 = lz[0], z1 = lz[1], z2 = lz[2], z3 = lz[3];
    int base = row0 * 128 + tid;
    out[base      ] = acc0 - z0;
    out[base + 128] = acc1 - z1;
    out[base + 256] = acc2 - z2;
    out[base + 384] = acc3 - z3;
}

extern "C" void kernel_launch(void* const* d_in, const int* in_sizes, int n_in,
                              void* d_out, int out_size, void* d_ws, size_t ws_size,
                              hipStream_t stream) {
    const float* inp     = (const float*)d_in[0];
    const float* img     = (const float*)d_in[1];
    const float* conv1_w = (const float*)d_in[2];
    const float* conv1_b = (const float*)d_in[3];
    const float* conv2_w = (const float*)d_in[4];
    const float* conv2_b = (const float*)d_in[5];
    const float* imgfc_w = (const float*)d_in[6];
    const float* imgfc_b = (const float*)d_in[7];
    const float* xh_w    = (const float*)d_in[8];
    const float* xh_b    = (const float*)d_in[9];
    const float* hh_w    = (const float*)d_in[10];
    const float* hh_b    = (const float*)d_in[11];
    const float* out_w   = (const float*)d_in[12];
    const float* out_b   = (const float*)d_in[13];

    // ws layout (peak 79 MB). conv1out/feat alias the hs region: both are
    // dead before the first cell_k writes hs[0].
    char* ws = (char*)d_ws;
    unsigned short* hs = (unsigned short*)(ws);                   // [0,64M): [T,B,512] bf16
    float* conv1out    = (float*)(ws);                            // [0,32M): [B,8,32,32] (dead after conv2)
    float* feat        = (float*)(ws + (32u << 20));              // [32,46.2M): [B,3600] (dead after imgfc)
    float* e           = (float*)(ws + (64u << 20));              // 2 MB
    float* hbuf        = (float*)(ws + (66u << 20));              // 2 MB
    float* cbuf        = (float*)(ws + (68u << 20));              // 2 MB
    float* cbias       = (float*)(ws + (70u << 20));              // 8 KB
    float* gates       = (float*)(ws + (71u << 20));              // 8 MB: [B,2048]
    float* outp        = (float*)d_out;

    init_k<<<(B_ * H_) / 256, 256, 0, stream>>>(xh_b, hh_b, hbuf, cbuf, cbias);
    conv1_k<<<(B_ * 8 * 32 * 32) / 256, 256, 0, stream>>>(img, conv1_w, conv1_b, conv1out);
    conv2_k<<<B_, 256, 0, stream>>>(conv1out, conv2_w, conv2_b, feat);
    imgfc_gemm<<<dim3(8, 16), 256, 0, stream>>>(feat, imgfc_w, imgfc_b, e);

    for (int t = 0; t < T_; ++t) {
        gates_gemm<<<dim3(32, 16), 256, 0, stream>>>(inp + (size_t)t * B_ * V_, hbuf, xh_w, hh_w,
                                                     cbias, e, gates, t == 0 ? 1 : 0);
        cell_k<<<(B_ * H_) / 256, 256, 0, stream>>>(gates, hbuf, cbuf, hs + (size_t)t * B_ * H_);
    }
    logits_k<<<(T_ * B_) / 4, 128, 0, stream>>>(hs, out_w, out_b, outp);
}

// Round 4
// 2608.572 us; speedup vs baseline: 1.5584x; 1.5584x over previous
//
#include <hip/hip_runtime.h>

// Model dims
#define T_ 64
#define B_ 1024
#define V_ 128
#define H_ 512

typedef short bf16x8 __attribute__((ext_vector_type(8)));
typedef float f32x4 __attribute__((ext_vector_type(4)));

__device__ __forceinline__ unsigned short f2bf(float f) {
    union { float f; unsigned int i; } v; v.f = f;
    unsigned int x = v.i;
    return (unsigned short)((x + 0x7FFFu + ((x >> 16) & 1u)) >> 16);
}
__device__ __forceinline__ float bf2f(unsigned short u) {
    union { unsigned int i; float f; } v; v.i = ((unsigned int)u) << 16; return v.f;
}

// ---------------- cbias = xh_b + hh_b ----------------
__global__ __launch_bounds__(256) void cbias_k(const float* __restrict__ xh_b,
                                               const float* __restrict__ hh_b,
                                               float* __restrict__ cbias) {
    int i = blockIdx.x * 256 + threadIdx.x;          // 2048
    cbias[i] = xh_b[i] + hh_b[i];
}

// ---------------- convert inp fp32 -> bf16 ----------------
__global__ __launch_bounds__(256) void convx_k(const float* __restrict__ x,
                                               unsigned short* __restrict__ xbf) {
    int i = blockIdx.x * 256 + threadIdx.x;          // T*B*V = 8388608
    xbf[i] = f2bf(x[i]);
}

// ---------------- build Wt bf16 [2048][640]: Wt[n][k] = W[k][n] ----------------
__global__ __launch_bounds__(256) void convw_k(const float* __restrict__ xw,
                                               const float* __restrict__ hw,
                                               unsigned short* __restrict__ wt) {
    int i = blockIdx.x * 256 + threadIdx.x;          // 2048*640 = 1310720
    int n = i / 640, k = i - n * 640;
    float v = (k < 128) ? xw[k * 2048 + n] : hw[(k - 128) * 2048 + n];
    wt[i] = f2bf(v);
}

// ---------------- conv1 3x3 pad1 + relu + 2x2 maxpool ----------------
__global__ __launch_bounds__(256) void conv1_k(const float* __restrict__ img,
                                               const float* __restrict__ w,
                                               const float* __restrict__ bias,
                                               float* __restrict__ out) {
    int id = blockIdx.x * 256 + threadIdx.x;         // B*8*32*32 = 8388608
    int px = id & 31, py = (id >> 5) & 31, oc = (id >> 10) & 7, b = id >> 13;
    const float* ip = img + b * 4096;
    float wv[9];
#pragma unroll
    for (int t = 0; t < 9; ++t) wv[t] = w[oc * 9 + t];
    float bs = bias[oc];
    float m = -3.4e38f;
#pragma unroll
    for (int sy = 0; sy < 2; ++sy)
#pragma unroll
    for (int sx = 0; sx < 2; ++sx) {
        int oy = 2 * py + sy, ox = 2 * px + sx;
        float acc = bs;
#pragma unroll
        for (int ky = 0; ky < 3; ++ky) {
            int iy = oy + ky - 1;
            if (iy < 0 || iy > 63) continue;
#pragma unroll
            for (int kx = 0; kx < 3; ++kx) {
                int ix = ox + kx - 1;
                if (ix < 0 || ix > 63) continue;
                acc += ip[iy * 64 + ix] * wv[ky * 3 + kx];
            }
        }
        m = fmaxf(m, acc);
    }
    out[id] = fmaxf(m, 0.f);
}

// ---------------- conv2 5x5 pad1 + relu + 2x2 maxpool ----------------
// even/odd-x split LDS layout [ic][y][2][18] -> stride-1 bank pattern
__device__ __forceinline__ int c2idx(int ic, int y, int x) {
    return ((ic * 34 + y) * 2 + (x & 1)) * 18 + (x >> 1);
}
__global__ __launch_bounds__(256) void conv2_k(const float* __restrict__ in,
                                               const float* __restrict__ w,
                                               const float* __restrict__ bias,
                                               float* __restrict__ feat) {
    __shared__ float in_s[8 * 34 * 36];
    __shared__ float w_s[3200];
    __shared__ float b_s[16];
    int tid = threadIdx.x, b = blockIdx.x;
    for (int e = tid; e < 8 * 34 * 34; e += 256) {
        int ic = e / 1156, r = e - ic * 1156;
        int y = r / 34, xx = r - y * 34;
        float v = 0.f;
        if (y >= 1 && y <= 32 && xx >= 1 && xx <= 32)
            v = in[b * 8192 + ic * 1024 + (y - 1) * 32 + (xx - 1)];
        in_s[c2idx(ic, y, xx)] = v;
    }
    for (int e = tid; e < 3200; e += 256) w_s[e] = w[e];
    if (tid < 16) b_s[tid] = bias[tid];
    __syncthreads();
    for (int o = tid; o < 3600; o += 256) {
        int oc = o / 225, p = o - oc * 225;
        int py = p / 15, px = p - py * 15;
        float a00, a01, a10, a11;
        a00 = a01 = a10 = a11 = b_s[oc];
        for (int ic = 0; ic < 8; ++ic) {
            const float* wp = w_s + (oc * 8 + ic) * 25;
#pragma unroll
            for (int ky = 0; ky < 5; ++ky) {
                int y0 = 2 * py + ky;
                float r0[6], r1[6];
#pragma unroll
                for (int xx = 0; xx < 6; ++xx) {
                    r0[xx] = in_s[c2idx(ic, y0,     2 * px + xx)];
                    r1[xx] = in_s[c2idx(ic, y0 + 1, 2 * px + xx)];
                }
#pragma unroll
                for (int kx = 0; kx < 5; ++kx) {
                    float wv = wp[ky * 5 + kx];
                    a00 += r0[kx    ] * wv;
                    a01 += r0[kx + 1] * wv;
                    a10 += r1[kx    ] * wv;
                    a11 += r1[kx + 1] * wv;
                }
            }
        }
        float mx = fmaxf(fmaxf(a00, a01), fmaxf(a10, a11));
        feat[b * 3600 + o] = fmaxf(mx, 0.f);
    }
}

// ---------------- imgfc: e = relu(feat @ W + b), M=1024 N=512 K=3600 ----------------
__global__ __launch_bounds__(256) void imgfc_gemm(const float* __restrict__ A,
                                                  const float* __restrict__ W,
                                                  const float* __restrict__ bias,
                                                  float* __restrict__ E) {
    __shared__ __align__(16) float As[16][68];
    __shared__ __align__(16) float Bs[16][68];
    const int tid = threadIdx.x;
    const int tx = tid & 15, ty = tid >> 4;
    const int row0 = blockIdx.y * 64, col0 = blockIdx.x * 64;
    const int am = tid >> 2, ak = (tid & 3) * 4;
    const int bk = tid >> 4, bn = (tid & 15) * 4;
    float acc[4][4] = {};
    for (int k0 = 0; k0 < 3600; k0 += 16) {
        float4 fa = *(const float4*)(A + (row0 + am) * 3600 + k0 + ak);
        float4 fb = *(const float4*)(W + (k0 + bk) * 512 + col0 + bn);
        __syncthreads();
        As[ak + 0][am] = fa.x; As[ak + 1][am] = fa.y; As[ak + 2][am] = fa.z; As[ak + 3][am] = fa.w;
        Bs[bk][bn + 0] = fb.x; Bs[bk][bn + 1] = fb.y; Bs[bk][bn + 2] = fb.z; Bs[bk][bn + 3] = fb.w;
        __syncthreads();
#pragma unroll
        for (int kk = 0; kk < 16; ++kk) {
            float4 av = *(const float4*)(&As[kk][ty * 4]);
            float4 bv = *(const float4*)(&Bs[kk][tx * 4]);
            float a[4] = {av.x, av.y, av.z, av.w};
            float bb[4] = {bv.x, bv.y, bv.z, bv.w};
#pragma unroll
            for (int i = 0; i < 4; ++i)
#pragma unroll
            for (int j = 0; j < 4; ++j) acc[i][j] += a[i] * bb[j];
        }
    }
#pragma unroll
    for (int i = 0; i < 4; ++i) {
        int r = row0 + ty * 4 + i;
#pragma unroll
        for (int j = 0; j < 4; ++j) {
            int cI = col0 + tx * 4 + j;
            E[r * 512 + cI] = fmaxf(acc[i][j] + bias[cI], 0.f);
        }
    }
}

// ---------------- fused LSTM step: gates MFMA GEMM + cell ----------------
// grid (32,16), block 256 = 4 waves. Wave w: rows [by*64+w*16, +16).
// Block cols: j-window j0=bx*16 replicated across the 4 gates.
// A = [x_t(bf16) | h_{t-1}(bf16)] (K=640), B = Wt[n][k] bf16.
__global__ __launch_bounds__(256) void lstm_step(const unsigned short* __restrict__ xt,   // [B,128] bf16
                                                 const unsigned short* __restrict__ hprev,// [B,512] bf16
                                                 const unsigned short* __restrict__ wt,   // [2048,640] bf16
                                                 const float* __restrict__ cbias,         // [2048]
                                                 const float* __restrict__ eimg,          // [B,512]
                                                 float* __restrict__ cbuf,                // [B,512]
                                                 unsigned short* __restrict__ hs_t,       // [B,512] bf16
                                                 int t0flag) {
    const int tid = threadIdx.x;
    const int wave = tid >> 6, lane = tid & 63;
    const int quad = lane >> 4, l16 = lane & 15;
    const int row0 = blockIdx.y * 64 + wave * 16;
    const int j0 = blockIdx.x * 16;
    const int arow = row0 + l16;
    const int kq = quad * 8;

    f32x4 acc[4] = {{0.f,0.f,0.f,0.f},{0.f,0.f,0.f,0.f},{0.f,0.f,0.f,0.f},{0.f,0.f,0.f,0.f}};
    const size_t nbase0 = (size_t)(0 * 512 + j0 + l16) * 640;
    const size_t nbase1 = (size_t)(1 * 512 + j0 + l16) * 640;
    const size_t nbase2 = (size_t)(2 * 512 + j0 + l16) * 640;
    const size_t nbase3 = (size_t)(3 * 512 + j0 + l16) * 640;

    // x-part: K 0..128
#pragma unroll
    for (int k0 = 0; k0 < 128; k0 += 32) {
        bf16x8 a = *(const bf16x8*)(xt + (size_t)arow * 128 + k0 + kq);
        bf16x8 b0 = *(const bf16x8*)(wt + nbase0 + k0 + kq);
        bf16x8 b1 = *(const bf16x8*)(wt + nbase1 + k0 + kq);
        bf16x8 b2 = *(const bf16x8*)(wt + nbase2 + k0 + kq);
        bf16x8 b3 = *(const bf16x8*)(wt + nbase3 + k0 + kq);
        acc[0] = __builtin_amdgcn_mfma_f32_16x16x32_bf16(a, b0, acc[0], 0, 0, 0);
        acc[1] = __builtin_amdgcn_mfma_f32_16x16x32_bf16(a, b1, acc[1], 0, 0, 0);
        acc[2] = __builtin_amdgcn_mfma_f32_16x16x32_bf16(a, b2, acc[2], 0, 0, 0);
        acc[3] = __builtin_amdgcn_mfma_f32_16x16x32_bf16(a, b3, acc[3], 0, 0, 0);
    }
    // h-part: K 128..640 (skip at t=0, h0 = 0)
    if (!t0flag) {
#pragma unroll 4
        for (int k0 = 0; k0 < 512; k0 += 32) {
            bf16x8 a = *(const bf16x8*)(hprev + (size_t)arow * 512 + k0 + kq);
            bf16x8 b0 = *(const bf16x8*)(wt + nbase0 + 128 + k0 + kq);
            bf16x8 b1 = *(const bf16x8*)(wt + nbase1 + 128 + k0 + kq);
            bf16x8 b2 = *(const bf16x8*)(wt + nbase2 + 128 + k0 + kq);
            bf16x8 b3 = *(const bf16x8*)(wt + nbase3 + 128 + k0 + kq);
            acc[0] = __builtin_amdgcn_mfma_f32_16x16x32_bf16(a, b0, acc[0], 0, 0, 0);
            acc[1] = __builtin_amdgcn_mfma_f32_16x16x32_bf16(a, b1, acc[1], 0, 0, 0);
            acc[2] = __builtin_amdgcn_mfma_f32_16x16x32_bf16(a, b2, acc[2], 0, 0, 0);
            acc[3] = __builtin_amdgcn_mfma_f32_16x16x32_bf16(a, b3, acc[3], 0, 0, 0);
        }
    }

    // epilogue: C/D layout col=lane&15, row=quad*4+reg
    const int j = j0 + l16;
    const float cb0 = cbias[j], cb1 = cbias[512 + j], cb2 = cbias[1024 + j], cb3 = cbias[1536 + j];
#pragma unroll
    for (int reg = 0; reg < 4; ++reg) {
        int row = row0 + quad * 4 + reg;
        size_t o = (size_t)row * 512 + j;
        float ea = t0flag ? eimg[o] : 0.f;
        float iv = acc[0][reg] + cb0 + ea;
        float fv = acc[1][reg] + cb1 + ea;
        float gv = acc[2][reg] + cb2 + ea;
        float ov = acc[3][reg] + cb3 + ea;
        iv = 1.f / (1.f + expf(-iv));
        fv = 1.f / (1.f + expf(-fv));
        gv = tanhf(gv);
        ov = 1.f / (1.f + expf(-ov));
        float c_old = t0flag ? 0.f : cbuf[o];
        float cn = fv * c_old + iv * gv;
        float hn = ov * tanhf(cn);
        cbuf[o] = cn;
        hs_t[o] = f2bf(hn);
    }
}

// ---------------- logits + log_softmax, 4 rows per block, fp32 out ----------------
__global__ __launch_bounds__(128) void logits_k(const unsigned short* __restrict__ hs,
                                                const float* __restrict__ ow,
                                                const float* __restrict__ ob,
                                                float* __restrict__ out) {
    __shared__ float hrow[4][512];
    __shared__ float ls[4][128];
    __shared__ float lz[4];
    int tid = threadIdx.x;
    int row0 = blockIdx.x * 4;
    for (int e = tid; e < 2048; e += 128) {
        int r = e >> 9, cc = e & 511;
        hrow[r][cc] = bf2f(hs[(row0 + r) * 512 + cc]);
    }
    __syncthreads();
    float bb = ob[tid];
    float acc0 = bb, acc1 = bb, acc2 = bb, acc3 = bb;
#pragma unroll 4
    for (int k = 0; k < 512; ++k) {
        float w = ow[k * 128 + tid];
        acc0 += hrow[0][k] * w;
        acc1 += hrow[1][k] * w;
        acc2 += hrow[2][k] * w;
        acc3 += hrow[3][k] * w;
    }
    ls[0][tid] = acc0; ls[1][tid] = acc1; ls[2][tid] = acc2; ls[3][tid] = acc3;
    __syncthreads();
    int g = tid >> 5, lane = tid & 31;
    float v0 = ls[g][lane], v1 = ls[g][lane + 32], v2 = ls[g][lane + 64], v3 = ls[g][lane + 96];
    float m = fmaxf(fmaxf(v0, v1), fmaxf(v2, v3));
#pragma unroll
    for (int off = 16; off > 0; off >>= 1) m = fmaxf(m, __shfl_xor(m, off, 32));
    float s = expf(v0 - m) + expf(v1 - m) + expf(v2 - m) + expf(v3 - m);
#pragma unroll
    for (int off = 16; off > 0; off >>= 1) s += __shfl_xor(s, off, 32);
    if (lane == 0) lz[g] = m + logf(s);
    __syncthreads();
    float z0 = lz[0], z1 = lz[1], z2 = lz[2], z3 = lz[3];
    int base = row0 * 128 + tid;
    out[base      ] = acc0 - z0;
    out[base + 128] = acc1 - z1;
    out[base + 256] = acc2 - z2;
    out[base + 384] = acc3 - z3;
}

extern "C" void kernel_launch(void* const* d_in, const int* in_sizes, int n_in,
                              void* d_out, int out_size, void* d_ws, size_t ws_size,
                              hipStream_t stream) {
    const float* inp     = (const float*)d_in[0];
    const float* img     = (const float*)d_in[1];
    const float* conv1_w = (const float*)d_in[2];
    const float* conv1_b = (const float*)d_in[3];
    const float* conv2_w = (const float*)d_in[4];
    const float* conv2_b = (const float*)d_in[5];
    const float* imgfc_w = (const float*)d_in[6];
    const float* imgfc_b = (const float*)d_in[7];
    const float* xh_w    = (const float*)d_in[8];
    const float* xh_b    = (const float*)d_in[9];
    const float* hh_w    = (const float*)d_in[10];
    const float* hh_b    = (const float*)d_in[11];
    const float* out_w   = (const float*)d_in[12];
    const float* out_b   = (const float*)d_in[13];

    // ws layout (~88 MB). conv1out/feat alias the hs region (dead before
    // the first lstm_step writes hs[0]).
    char* ws = (char*)d_ws;
    unsigned short* hs  = (unsigned short*)(ws);                   // [0,64M): [T,B,512] bf16
    float* conv1out     = (float*)(ws);                            // [0,32M) alias
    float* feat         = (float*)(ws + (32u << 20));              // [32,46.2M) alias
    float* e            = (float*)(ws + (64u << 20));              // 2 MB
    float* cbuf         = (float*)(ws + (66u << 20));              // 2 MB
    float* cbias        = (float*)(ws + (68u << 20));              // 8 KB
    unsigned short* xbf = (unsigned short*)(ws + (69u << 20));     // 16 MB: [T,B,128] bf16
    unsigned short* wt  = (unsigned short*)(ws + (85u << 20));     // 2.56 MB: [2048,640] bf16
    float* outp         = (float*)d_out;

    cbias_k<<<8, 256, 0, stream>>>(xh_b, hh_b, cbias);
    convx_k<<<(T_ * B_ * V_) / 256, 256, 0, stream>>>(inp, xbf);
    convw_k<<<(2048 * 640) / 256, 256, 0, stream>>>(xh_w, hh_w, wt);
    conv1_k<<<(B_ * 8 * 32 * 32) / 256, 256, 0, stream>>>(img, conv1_w, conv1_b, conv1out);
    conv2_k<<<B_, 256, 0, stream>>>(conv1out, conv2_w, conv2_b, feat);
    imgfc_gemm<<<dim3(8, 16), 256, 0, stream>>>(feat, imgfc_w, imgfc_b, e);

    for (int t = 0; t < T_; ++t) {
        lstm_step<<<dim3(32, 16), 256, 0, stream>>>(
            xbf + (size_t)t * B_ * V_,
            hs + (size_t)(t > 0 ? t - 1 : 0) * B_ * H_,
            wt, cbias, e, cbuf,
            hs + (size_t)t * B_ * H_,
            t == 0 ? 1 : 0);
    }
    logits_k<<<(T_ * B_) / 4, 128, 0, stream>>>(hs, out_w, out_b, outp);
}